// Round 8
// baseline (1483.996 us; speedup 1.0000x reference)
//
#include <hip/hip_runtime.h>
#include <cstdint>
#include <cstddef>

typedef unsigned short u16;
typedef __attribute__((ext_vector_type(8))) short short8;
typedef __attribute__((ext_vector_type(4))) short short4v;
typedef __attribute__((ext_vector_type(4))) float f32x4;

__device__ __forceinline__ float b2f(u16 u){ return __uint_as_float(((unsigned)u)<<16); }
__device__ __forceinline__ u16 f2b(float f){
    unsigned u = __float_as_uint(f);
    return (u16)((u + 0x7fffu + ((u>>16)&1u)) >> 16);
}
__device__ __forceinline__ u16 f2b_fast(float f){          // round-half-up (2 ops)
    return (u16)((__float_as_uint(f) + 0x8000u) >> 16);
}
__device__ __forceinline__ int iclamp(int v, int lo, int hi){ return v<lo?lo:(v>hi?hi:v); }

// LDS-only barrier: no vmcnt(0) drain (global loads/stores stay in flight)
__device__ __forceinline__ void barrier_lds(){
    asm volatile("s_waitcnt lgkmcnt(0)\n\ts_barrier" ::: "memory");
}

// 8-wide f32 -> bf16 fragment
__device__ __forceinline__ short8 ld8f(const float* p){
    f32x4 a = *(const f32x4*)p;
    f32x4 b = *(const f32x4*)(p+4);
    short8 r;
    #pragma unroll
    for(int j=0;j<4;j++){ r[j]=(short)f2b(a[j]); r[4+j]=(short)f2b(b[j]); }
    return r;
}
__device__ __forceinline__ short8 ld8b(const u16* p){ return *(const short8*)p; }

// =============== 64x64-tile BT GEMM: C(MxN) = A(MxK) @ B(NxK)^T (+bias f32), bf16 out ===
// grid (M/64, N/64), block 256 (4 waves, each 32x32 output).
template<bool TRANSOUT, bool RELU, bool AF32, bool BF32>
__global__ __launch_bounds__(256) void gemm64(
    const void* __restrict__ A, const void* __restrict__ B,
    const float* __restrict__ bias, u16* __restrict__ C,
    int M, int N, int K, int ldb, int ldc)
{
    constexpr int BK=32;
    __shared__ u16 As[64][BK+8];
    __shared__ u16 Bs[64][BK+8];
    const int tid = threadIdx.x;
    const int bm = blockIdx.x*64, bn = blockIdx.y*64;
    const int wave = tid>>6, lane = tid&63, lm = lane&15, lg = lane>>4;
    const int wm = (wave>>1)*32, wn = (wave&1)*32;
    f32x4 acc[2][2];
    #pragma unroll
    for(int i=0;i<2;i++){ acc[i][0]=(f32x4){0.f,0.f,0.f,0.f}; acc[i][1]=(f32x4){0.f,0.f,0.f,0.f}; }

    const int arow = tid>>2, akc = (tid&3)*8;
    for(int k0=0;k0<K;k0+=BK){
        *(short8*)&As[arow][akc] = AF32 ? ld8f((const float*)A + (size_t)(bm+arow)*K + k0+akc)
                                        : ld8b((const u16*)A + (size_t)(bm+arow)*K + k0+akc);
        *(short8*)&Bs[arow][akc] = BF32 ? ld8f((const float*)B + (size_t)(bn+arow)*ldb + k0+akc)
                                        : ld8b((const u16*)B + (size_t)(bn+arow)*ldb + k0+akc);
        __syncthreads();
        short8 af[2], bfg[2];
        #pragma unroll
        for(int mt=0;mt<2;mt++) af[mt]  = *(const short8*)&As[wm+mt*16+lm][lg*8];
        #pragma unroll
        for(int nt=0;nt<2;nt++) bfg[nt] = *(const short8*)&Bs[wn+nt*16+lm][lg*8];
        #pragma unroll
        for(int nt=0;nt<2;nt++)
            #pragma unroll
            for(int mt=0;mt<2;mt++)
                acc[mt][nt] = __builtin_amdgcn_mfma_f32_16x16x32_bf16(af[mt], bfg[nt], acc[mt][nt], 0,0,0);
        __syncthreads();
    }
    #pragma unroll
    for(int nt=0;nt<2;nt++){
        const int col = bn+wn+nt*16+lm;
        const float bv = bias ? bias[col] : 0.f;
        #pragma unroll
        for(int mt=0;mt<2;mt++){
            const int row0 = bm+wm+mt*16+lg*4;
            #pragma unroll
            for(int r=0;r<4;r++){
                const int row = row0+r;
                float v = acc[mt][nt][r] + bv;
                if(RELU) v = fmaxf(v, 0.f);
                const size_t idx = TRANSOUT ? ((size_t)col*ldc + row) : ((size_t)row*ldc + col);
                C[idx] = f2b(v);
            }
        }
    }
}

// =============== h1_pre = skill_emb @ gcn_w1^T   (101x8, f32 in/out), 8 blocks ========
__global__ __launch_bounds__(256) void k_h1pre(const float* __restrict__ skill_emb,
                                               const float* __restrict__ gcn_w1,
                                               float* __restrict__ h1pre)
{
    if(threadIdx.x >= 101) return;
    const int idx = blockIdx.x*101 + threadIdx.x;
    if(idx>=808) return;
    const int n=idx>>3, j=idx&7;
    const float* x = skill_emb + n*256;
    const float* w = gcn_w1 + j*256;
    float acc=0.f;
    for(int k=0;k<256;k+=4){
        f32x4 a = *(const f32x4*)&x[k];
        f32x4 b = *(const f32x4*)&w[k];
        acc += a.x*b.x + a.y*b.y + a.z*b.z + a.w*b.w;
    }
    h1pre[idx]=acc;
}

// =============== per-batch skill GCN, softmax pooling -> pooled (64x256 f32) ===============
__global__ __launch_bounds__(256) void k_gcn(
    const int* __restrict__ skill, const int* __restrict__ answer,
    const float* __restrict__ pos, const float* __restrict__ h1pre,
    const float* __restrict__ gcn_b1, const float* __restrict__ gcn_w2, const float* __restrict__ gcn_b2,
    float* __restrict__ pooled)
{
    const int b = blockIdx.x, tid = threadIdx.x;
    __shared__ int   sk[500];
    __shared__ float msk[500];
    __shared__ float coef[500];
    __shared__ float deg[101];
    __shared__ float agg1[101*8];
    __shared__ float agg2[101*8];
    __shared__ float red[256];
    __shared__ float vec8[8];
    __shared__ float sS[1];

    for(int i=tid;i<500;i+=256){
        sk[i]=iclamp(skill[b*500+i],0,100);
        msk[i] = (answer[b*500+i]!=2)?1.f:0.f;
    }
    for(int i=tid;i<101;i+=256) deg[i]=1.f;           // self loop
    if(tid<8)  vec8[tid]=0.f;
    if(tid==8) sS[0]=0.f;
    __syncthreads();
    for(int e=tid;e<499;e+=256) atomicAdd(&deg[sk[e+1]], 1.f);
    __syncthreads();
    for(int i=tid;i<101;i+=256) deg[i] = rsqrtf(deg[i]);   // deg -> dinv
    float cnt=0.f; for(int i=tid;i<500;i+=256) cnt += msk[i];
    __syncthreads();
    red[tid]=cnt; __syncthreads();
    for(int s=128;s>0;s>>=1){ if(tid<s) red[tid]+=red[tid+s]; __syncthreads(); }
    const int len = iclamp((int)(red[0]+0.5f), 1, 500);
    __syncthreads();
    for(int i=tid;i<808;i+=256){ const int n=i>>3; agg1[i] = deg[n]*deg[n]*h1pre[i]; }
    __syncthreads();
    for(int i=tid;i<499*8;i+=256){
        const int e=i>>3, j=i&7, s=sk[e], d=sk[e+1];
        atomicAdd(&agg1[d*8+j], deg[s]*deg[d]*h1pre[s*8+j]);
    }
    __syncthreads();
    for(int i=tid;i<808;i+=256){ const int j=i&7; agg1[i] = fmaxf(agg1[i]+gcn_b1[j], 0.f); }
    __syncthreads();
    for(int i=tid;i<808;i+=256){ const int n=i>>3; agg2[i] = deg[n]*deg[n]*agg1[i]; }
    __syncthreads();
    for(int i=tid;i<499*8;i+=256){
        const int e=i>>3, j=i&7, s=sk[e], d=sk[e+1];
        atomicAdd(&agg2[d*8+j], deg[s]*deg[d]*agg1[s*8+j]);
    }
    const size_t prow = (size_t)(len-1)*500;
    float vmax = -1e30f;
    for(int i=tid;i<500;i+=256){ const float v = pos[prow+i]*msk[i]; coef[i]=v; vmax=fmaxf(vmax,v); }
    red[tid]=vmax; __syncthreads();           // also orders agg2 atomics
    for(int s=128;s>0;s>>=1){ if(tid<s) red[tid]=fmaxf(red[tid],red[tid+s]); __syncthreads(); }
    const float m = red[0]; __syncthreads();
    float lsum=0.f;
    for(int i=tid;i<500;i+=256){ const float e=__expf(coef[i]-m); coef[i]=e; lsum+=e; }
    red[tid]=lsum; __syncthreads();
    for(int s=128;s>0;s>>=1){ if(tid<s) red[tid]+=red[tid+s]; __syncthreads(); }
    const float inv = 1.f/red[0];
    __syncthreads();
    float v8[8]={0,0,0,0,0,0,0,0}; float ls=0.f;
    for(int i=tid;i<500;i+=256){
        const float ci = coef[i]*inv*msk[i];
        if(ci!=0.f){
            const int n=sk[i]; ls+=ci;
            #pragma unroll
            for(int j=0;j<8;j++) v8[j] += ci*agg2[n*8+j];
        }
    }
    #pragma unroll
    for(int j=0;j<8;j++) atomicAdd(&vec8[j], v8[j]);
    atomicAdd(&sS[0], ls);
    __syncthreads();
    {
        const int o = tid;
        float acc = gcn_b2[o]*sS[0];
        #pragma unroll
        for(int j=0;j<8;j++) acc += vec8[j]*gcn_w2[o*8+j];
        pooled[b*256+o] = acc;
    }
}

// ====== x-part tables: table[combo] = x(skill,answer) @ Wih[:,256:768]^T + bih + bhh ======
__global__ __launch_bounds__(256) void k_table(
    const float* __restrict__ skill_emb, const float* __restrict__ answer_emb,
    const float* __restrict__ wih, const float* __restrict__ bih, const float* __restrict__ bhh,
    float* __restrict__ table)
{
    const int combo = blockIdx.x, tid = threadIdx.x;
    const int sid = combo/3, ans = combo - sid*3;
    __shared__ float sf[256], sg[256];
    sf[tid] = (ans==1) ? skill_emb[(size_t)sid*256+tid] : answer_emb[(size_t)ans*256+tid];
    sg[tid] = (ans==1) ? answer_emb[(size_t)ans*256+tid] : skill_emb[(size_t)sid*256+tid];
    __syncthreads();
    const int o = tid;
    float acc = bih[o] + bhh[o];
    const float* w = wih + (size_t)o*768;
    for(int k=0;k<256;k+=4){
        f32x4 w1v = *(const f32x4*)&w[256+k];
        f32x4 w2v = *(const f32x4*)&w[512+k];
        acc += sf[k]*w1v.x + sf[k+1]*w1v.y + sf[k+2]*w1v.z + sf[k+3]*w1v.w;
        acc += sg[k]*w2v.x + sg[k+1]*w2v.y + sg[k+2]*w2v.z + sg[k+3]*w2v.w;
    }
    table[(size_t)combo*256 + o] = acc;
}

// =============== pooled_proj[b] = pooled[b] @ dg_wih[:, :256]^T  (bf16 64x256) ===============
__global__ __launch_bounds__(256) void k_pooledproj(const float* __restrict__ pooled,
                                                    const float* __restrict__ wih,
                                                    u16* __restrict__ outp)
{
    const int b=blockIdx.x, tid=threadIdx.x;
    __shared__ float p[256];
    p[tid] = pooled[b*256+tid];
    __syncthreads();
    const float* w = wih + (size_t)tid*768;
    float acc=0.f;
    for(int k=0;k<256;k+=4){
        f32x4 wv = *(const f32x4*)&w[k];
        acc += p[k]*wv.x + p[k+1]*wv.y + p[k+2]*wv.z + p[k+3]*wv.w;
    }
    outp[b*256+tid]=f2b(acc);
}

// ====== k_pre: pre[rnn][t][b][c] = table[combo(t,b)] + proj  (bf16, t-major) ======
// grid (500, 2, 4), block 256.  Indices computed inline (k_idx folded in).
__global__ __launch_bounds__(256) void k_pre(
    const int* __restrict__ skill, const int* __restrict__ answer, const int* __restrict__ student,
    const float* __restrict__ table_dg, const float* __restrict__ table_hg,
    const u16* __restrict__ pooled_proj, const u16* __restrict__ stu_proj,
    u16* __restrict__ pre_dg, u16* __restrict__ pre_hg)
{
    const int t = blockIdx.x, rnn = blockIdx.y, c = threadIdx.x;
    const int b0 = blockIdx.z*16;
    const float* tab = rnn ? table_hg : table_dg;
    u16* outp = rnn ? pre_hg : pre_dg;
    for(int b=b0;b<b0+16;b++){
        const int sk = iclamp(skill[b*500+t], 0, 100);
        const int an = iclamp(answer[b*500+t], 0, 2);
        const int cmb = sk*3+an;
        const u16* prow = rnn ? (stu_proj + (size_t)iclamp(student[b*500+t]-1,0,4095)*256)
                              : (pooled_proj + (size_t)b*256);
        const float v = tab[(size_t)cmb*256 + c] + b2f(prow[c]);
        outp[((size_t)t*64+b)*256 + c] = f2b(v);
    }
}

// =============== RNN v5: 2 fat waves/block, W fully register-resident (256 VGPR) ======
// 8 blocks = (rnn, 16-row group); wave owns output cols [wave*128, +128) = 8 col-tiles.
// Per CU-step LDS reads: 2 waves x 8 ds_read_b128 = 16 (was 64); each read feeds 8 MFMAs.
__global__ __launch_bounds__(128,1) void k_rnn(
    const u16* __restrict__ pre_dg, const u16* __restrict__ pre_hg,
    const float* __restrict__ whh_dg, const float* __restrict__ whh_hg,
    u16* __restrict__ hall_dg, u16* __restrict__ hall_hg)
{
    __shared__ u16 hc[2][8][4][16][8];    // 2 x 8KB, fragment chunk layout
    const int bid = blockIdx.x;
    const int rnn = bid>>2, grp = bid&3, rb = grp*16;
    const float* W   = rnn ? whh_hg : whh_dg;
    const u16*  pre  = rnn ? pre_hg : pre_dg;
    u16*        out  = rnn ? hall_hg : hall_dg;
    const int tid = threadIdx.x, wave = tid>>6, lane = tid&63;
    const int lm = lane&15, lg = lane>>4;
    const int cb = wave*128;

    // W fragments as A-operand (row = output col), fully register-resident: 8 tiles x 8 kk
    short8 wf[8][8];
    #pragma unroll
    for(int t8=0;t8<8;t8++)
        #pragma unroll
        for(int kk=0;kk<8;kk++)
            wf[t8][kk] = ld8f(W + (size_t)(cb+t8*16+lm)*256 + kk*32 + lg*8);

    for(int i=tid;i<2*8*4*16*8;i+=128) ((u16*)hc)[i]=0;

    const size_t rowoff = (size_t)(rb+lm)*256;
    uint2 pv[8];
    #pragma unroll
    for(int t8=0;t8<8;t8++)
        pv[t8] = *(const uint2*)&pre[rowoff + cb + t8*16 + lg*4];
    __syncthreads();

    int cur = 0;
    for(int t=0;t<500;t++){
        f32x4 acc[8];
        #pragma unroll
        for(int t8=0;t8<8;t8++) acc[t8]=(f32x4){0.f,0.f,0.f,0.f};
        // 8 reads, each feeding 8 MFMAs (8 independent accumulator chains)
        #pragma unroll
        for(int kk=0;kk<8;kk++){
            short8 hb = *(const short8*)&hc[cur][kk][lg][lm][0];
            #pragma unroll
            for(int t8=0;t8<8;t8++)
                acc[t8] = __builtin_amdgcn_mfma_f32_16x16x32_bf16(wf[t8][kk], hb, acc[t8], 0,0,0);
        }
        // prefetch next step's pre
        uint2 pvn[8];
        {
            const int tn = (t<499)? t+1 : 499;
            const size_t base = (size_t)tn*64*256 + rowoff;
            #pragma unroll
            for(int t8=0;t8<8;t8++)
                pvn[t8] = *(const uint2*)&pre[base + cb + t8*16 + lg*4];
        }
        // epilogue: lane holds rows=lm, cols cb+t8*16+lg*4..+3
        #pragma unroll
        for(int t8=0;t8<8;t8++){
            const unsigned plo = pv[t8].x, phi = pv[t8].y;
            u16 hv[4];
            #pragma unroll
            for(int r=0;r<4;r++){
                const u16 pb = (u16)(((r<2)? plo : phi) >> ((r&1)*16));
                const float v = acc[t8][r] + b2f(pb);
                const float e = __expf(2.f*v);
                const float th = 1.f - 2.f*__builtin_amdgcn_rcpf(e+1.f);  // tanh
                hv[r] = f2b_fast(th);
            }
            uint2 pk;
            pk.x = (unsigned)hv[0] | ((unsigned)hv[1]<<16);
            pk.y = (unsigned)hv[2] | ((unsigned)hv[3]<<16);
            // chunk dest for col c = cb + t8*16 + lg*4: kk'=wave*4+(t8>>1), lg'=(t8&1)*2+(lg>>1)
            *(uint2*)&hc[cur^1][wave*4+(t8>>1)][(t8&1)*2+(lg>>1)][lm][(lg&1)*4] = pk;
            *(uint2*)&out[(size_t)t*64*256 + rowoff + cb + t8*16 + lg*4] = pk;
        }
        barrier_lds();      // LDS-visibility only: global loads/stores stay in flight
        #pragma unroll
        for(int t8=0;t8<8;t8++) pv[t8]=pvn[t8];
        cur ^= 1;
    }
}

// ====== theta = sigmoid(h_hg@w1^T + h_dg@w2^T + b1 + b2), dual-GEMM fused, bf16 out ======
// grid (250, 4), block 256.  M=32000, N=256, K=256.
__global__ __launch_bounds__(256) void k_theta(
    const u16* __restrict__ Ah, const u16* __restrict__ Ad,
    const float* __restrict__ w1, const float* __restrict__ w2,
    const float* __restrict__ b1, const float* __restrict__ b2,
    u16* __restrict__ theta)
{
    constexpr int BK=32;
    __shared__ u16 AsH[128][BK+8];
    __shared__ u16 AsD[128][BK+8];
    __shared__ u16 BsH[64][BK+8];
    __shared__ u16 BsD[64][BK+8];
    const int tid = threadIdx.x;
    const int bm = blockIdx.x*128, bn = blockIdx.y*64;
    const int wave = tid>>6, lane = tid&63, lm = lane&15, lg = lane>>4;
    const int wm = (wave>>1)*64, wn = (wave&1)*32;
    f32x4 acc[4][2];
    #pragma unroll
    for(int i=0;i<4;i++){ acc[i][0]=(f32x4){0.f,0.f,0.f,0.f}; acc[i][1]=(f32x4){0.f,0.f,0.f,0.f}; }

    const int arow0 = tid>>2, akc0 = (tid&3)*8;
    const int arow1 = arow0 + 64;
    for(int k0=0;k0<256;k0+=BK){
        *(short8*)&AsH[arow0][akc0] = ld8b(Ah + (size_t)(bm+arow0)*256 + k0+akc0);
        *(short8*)&AsH[arow1][akc0] = ld8b(Ah + (size_t)(bm+arow1)*256 + k0+akc0);
        *(short8*)&AsD[arow0][akc0] = ld8b(Ad + (size_t)(bm+arow0)*256 + k0+akc0);
        *(short8*)&AsD[arow1][akc0] = ld8b(Ad + (size_t)(bm+arow1)*256 + k0+akc0);
        *(short8*)&BsH[arow0][akc0] = ld8f(w1 + (size_t)(bn+arow0)*256 + k0+akc0);
        *(short8*)&BsD[arow0][akc0] = ld8f(w2 + (size_t)(bn+arow0)*256 + k0+akc0);
        __syncthreads();
        short8 afH[4], afD[4], bf1[2], bf2[2];
        #pragma unroll
        for(int mt=0;mt<4;mt++){
            afH[mt] = *(const short8*)&AsH[wm+mt*16+lm][lg*8];
            afD[mt] = *(const short8*)&AsD[wm+mt*16+lm][lg*8];
        }
        #pragma unroll
        for(int nt=0;nt<2;nt++){
            bf1[nt] = *(const short8*)&BsH[wn+nt*16+lm][lg*8];
            bf2[nt] = *(const short8*)&BsD[wn+nt*16+lm][lg*8];
        }
        #pragma unroll
        for(int nt=0;nt<2;nt++)
            #pragma unroll
            for(int mt=0;mt<4;mt++){
                acc[mt][nt] = __builtin_amdgcn_mfma_f32_16x16x32_bf16(afH[mt], bf1[nt], acc[mt][nt], 0,0,0);
                acc[mt][nt] = __builtin_amdgcn_mfma_f32_16x16x32_bf16(afD[mt], bf2[nt], acc[mt][nt], 0,0,0);
            }
        __syncthreads();
    }
    #pragma unroll
    for(int nt=0;nt<2;nt++){
        const int col = bn+wn+nt*16+lm;
        const float bb = b1[col]+b2[col];
        #pragma unroll
        for(int mt=0;mt<4;mt++){
            const int row0 = bm+wm+mt*16+lg*4;
            #pragma unroll
            for(int r=0;r<4;r++){
                const float x = acc[mt][nt][r] + bb;
                theta[(size_t)(row0+r)*256 + col] = f2b(1.f/(1.f+__expf(-x)));
            }
        }
    }
}

// =============== final gather: one wave per (b,t), three outputs ===============
__global__ __launch_bounds__(256) void k_out(
    const int* __restrict__ skill,
    const u16* __restrict__ hall_hg, const u16* __restrict__ hall_dg,
    const u16* __restrict__ theta,
    const float* __restrict__ fc_h_w, const float* __restrict__ fc_h_b,
    const float* __restrict__ fc_d_w, const float* __restrict__ fc_d_b,
    const float* __restrict__ fc_e_w, const float* __restrict__ fc_e_b,
    float* __restrict__ outp)
{
    const int tid=threadIdx.x, lane=tid&63;
    const int wid = blockIdx.x*4 + (tid>>6);        // 0..31935
    const int b = wid/499, t = wid - b*499;
    const int ns = skill[b*500 + t + 1];
    float o0=0.f,o1=0.f,o2=0.f,bh=0.f,bd=0.f,be=0.f;
    if(ns != 100){
        const int c = iclamp(ns, 0, 99);
        const size_t r = (size_t)t*64 + b;
        const int k = lane*4;
        short4v hh  = *(const short4v*)&hall_hg[r*256+k];
        short4v hd  = *(const short4v*)&hall_dg[r*256+k];
        short4v th  = *(const short4v*)&theta[r*256+k];
        f32x4 fh  = *(const f32x4*)&fc_h_w[(size_t)c*256+k];
        f32x4 fd  = *(const f32x4*)&fc_d_w[(size_t)c*256+k];
        f32x4 fe1 = *(const f32x4*)&fc_e_w[(size_t)c*512+k];
        f32x4 fe2 = *(const f32x4*)&fc_e_w[(size_t)c*512+256+k];
        #pragma unroll
        for(int j=0;j<4;j++){
            const float hhj=b2f((u16)hh[j]), hdj=b2f((u16)hd[j]), tj=b2f((u16)th[j]);
            o0 += hhj*fh[j];
            o1 += hdj*fd[j];
            o2 += tj*hhj*fe1[j] + (1.f-tj)*hdj*fe2[j];
        }
        #pragma unroll
        for(int off=32;off>0;off>>=1){
            o0 += __shfl_down(o0,off);
            o1 += __shfl_down(o1,off);
            o2 += __shfl_down(o2,off);
        }
        bh=fc_h_b[c]; bd=fc_d_b[c]; be=fc_e_b[c];
    }
    if(lane==0){
        outp[            b*499+t] = (ns==100)?0.f:(o0+bh);
        outp[31936     + b*499+t] = (ns==100)?0.f:(o1+bd);
        outp[2*31936   + b*499+t] = (ns==100)?0.f:(o2+be);
    }
}

// ================================= launch =================================
extern "C" void kernel_launch(void* const* d_in, const int* in_sizes, int n_in,
                              void* d_out, int out_size, void* d_ws, size_t ws_size,
                              hipStream_t stream)
{
    const int* student = (const int*)d_in[0];
    const int* skill   = (const int*)d_in[1];
    const int* answer  = (const int*)d_in[2];
    const float* G        = (const float*)d_in[3];
    const float* skill_emb= (const float*)d_in[4];
    const float* answer_emb=(const float*)d_in[5];
    const float* stu      = (const float*)d_in[6];
    const float* hg_w1    = (const float*)d_in[7];
    const float* hg_b1    = (const float*)d_in[8];
    const float* hg_w2    = (const float*)d_in[9];
    const float* hg_b2    = (const float*)d_in[10];
    const float* gcn_w1   = (const float*)d_in[11];
    const float* gcn_b1   = (const float*)d_in[12];
    const float* gcn_w2   = (const float*)d_in[13];
    const float* gcn_b2   = (const float*)d_in[14];
    const float* w1_w     = (const float*)d_in[15];
    const float* w1_b     = (const float*)d_in[16];
    const float* w2_w     = (const float*)d_in[17];
    const float* w2_b     = (const float*)d_in[18];
    const float* fc_d_w   = (const float*)d_in[19];
    const float* fc_d_b   = (const float*)d_in[20];
    const float* fc_h_w   = (const float*)d_in[21];
    const float* fc_h_b   = (const float*)d_in[22];
    const float* fc_e_w   = (const float*)d_in[23];
    const float* fc_e_b   = (const float*)d_in[24];
    const float* pos      = (const float*)d_in[25];
    const float* dg_wih   = (const float*)d_in[26];
    const float* dg_whh   = (const float*)d_in[27];
    const float* dg_bih   = (const float*)d_in[28];
    const float* dg_bhh   = (const float*)d_in[29];
    const float* hgr_wih  = (const float*)d_in[30];
    const float* hgr_whh  = (const float*)d_in[31];
    const float* hgr_bih  = (const float*)d_in[32];
    const float* hgr_bhh  = (const float*)d_in[33];

    char* ws = (char*)d_ws;
    size_t off = 0;
    auto nxt = [&](size_t bytes)->char*{
        char* r = ws + off;
        off += (bytes + 255) & ~(size_t)255;
        return r;
    };
    float* h1pre      = (float*)nxt(808*4);
    float* pooled     = (float*)nxt(64*256*4);
    float* table_dg   = (float*)nxt(303*256*4);
    float* table_hg   = (float*)nxt(303*256*4);
    u16*   tmpT       = (u16*)  nxt((size_t)256*4096*2);
    u16*   hbuf       = (u16*)  nxt((size_t)4096*256*2);
    u16*   stu_proj   = (u16*)  nxt((size_t)4096*256*2);
    u16*   pooled_proj= (u16*)  nxt(64*256*2);
    u16*   hall_dg    = (u16*)  nxt((size_t)32000*256*2);   // 16.4 MB
    u16*   hall_hg    = (u16*)  nxt((size_t)32000*256*2);   // 16.4 MB
    u16*   pre_dg     = (u16*)  nxt((size_t)32000*256*2);   // 16.4 MB (reused as theta)
    u16*   pre_hg     = (u16*)  nxt((size_t)32000*256*2);   // 16.4 MB
    u16*   theta      = pre_dg;                              // pre_dg dead after k_rnn

    // small prep
    k_h1pre<<<8,256,0,stream>>>(skill_emb, gcn_w1, h1pre);
    k_gcn<<<64,256,0,stream>>>(skill, answer, pos, h1pre, gcn_b1, gcn_w2, gcn_b2, pooled);
    k_table<<<303,256,0,stream>>>(skill_emb, answer_emb, dg_wih,  dg_bih,  dg_bhh,  table_dg);
    k_table<<<303,256,0,stream>>>(skill_emb, answer_emb, hgr_wih, hgr_bih, hgr_bhh, table_hg);

    // student GCN chain (G read as f32 directly; staging converts)
    gemm64<true ,false,true ,true ><<<dim3(64,4),256,0,stream>>>(stu,  hg_w1, hg_b1, tmpT, 4096,256,256,  256, 4096);
    gemm64<false,true ,true ,false><<<dim3(64,4),256,0,stream>>>(G,    tmpT,  nullptr, hbuf, 4096,256,4096, 4096, 256);
    gemm64<true ,false,false,true ><<<dim3(64,4),256,0,stream>>>(hbuf, hg_w2, hg_b2, tmpT, 4096,256,256,  256, 4096);
    gemm64<false,false,true ,false><<<dim3(64,4),256,0,stream>>>(G,    tmpT,  nullptr, hbuf, 4096,256,4096, 4096, 256);
    gemm64<false,false,false,true ><<<dim3(64,4),256,0,stream>>>(hbuf, hgr_wih, nullptr, stu_proj, 4096,256,256, 768, 256);

    k_pooledproj<<<64,256,0,stream>>>(pooled, dg_wih, pooled_proj);

    // fused pre-activation array (t-major bf16), indices inline
    k_pre<<<dim3(500,2,4),256,0,stream>>>(skill, answer, student, table_dg, table_hg,
                                          pooled_proj, stu_proj, pre_dg, pre_hg);

    // recurrences: 2 fat waves per block, W register-resident
    k_rnn<<<8,128,0,stream>>>(pre_dg, pre_hg, dg_whh, hgr_whh, hall_dg, hall_hg);

    // theta + outputs
    k_theta<<<dim3(250,4),256,0,stream>>>(hall_hg, hall_dg, w1_w, w2_w, w1_b, w2_b, theta);
    k_out<<<7984,256,0,stream>>>(skill, hall_hg, hall_dg, theta,
                                 fc_h_w, fc_h_b, fc_d_w, fc_d_b, fc_e_w, fc_e_b,
                                 (float*)d_out);
}

// Round 9
// 1083.140 us; speedup vs baseline: 1.3701x; 1.3701x over previous
//
#include <hip/hip_runtime.h>
#include <cstdint>
#include <cstddef>

typedef unsigned short u16;
typedef __attribute__((ext_vector_type(8))) short short8;
typedef __attribute__((ext_vector_type(4))) short short4v;
typedef __attribute__((ext_vector_type(4))) float f32x4;

__device__ __forceinline__ float b2f(u16 u){ return __uint_as_float(((unsigned)u)<<16); }
__device__ __forceinline__ u16 f2b(float f){
    unsigned u = __float_as_uint(f);
    return (u16)((u + 0x7fffu + ((u>>16)&1u)) >> 16);
}
__device__ __forceinline__ u16 f2b_fast(float f){          // round-half-up (2 ops)
    return (u16)((__float_as_uint(f) + 0x8000u) >> 16);
}
__device__ __forceinline__ int iclamp(int v, int lo, int hi){ return v<lo?lo:(v>hi?hi:v); }

// LDS-only barrier: no vmcnt(0) drain (global loads/stores stay in flight)
__device__ __forceinline__ void barrier_lds(){
    asm volatile("s_waitcnt lgkmcnt(0)\n\ts_barrier" ::: "memory");
}

// 8-wide f32 -> bf16 fragment
__device__ __forceinline__ short8 ld8f(const float* p){
    f32x4 a = *(const f32x4*)p;
    f32x4 b = *(const f32x4*)(p+4);
    short8 r;
    #pragma unroll
    for(int j=0;j<4;j++){ r[j]=(short)f2b(a[j]); r[4+j]=(short)f2b(b[j]); }
    return r;
}
__device__ __forceinline__ short8 ld8b(const u16* p){ return *(const short8*)p; }

// =============== 64x64-tile BT GEMM: C(MxN) = A(MxK) @ B(NxK)^T (+bias f32), bf16 out ===
// grid (M/64, N/64), block 256 (4 waves, each 32x32 output).
template<bool TRANSOUT, bool RELU, bool AF32, bool BF32>
__global__ __launch_bounds__(256) void gemm64(
    const void* __restrict__ A, const void* __restrict__ B,
    const float* __restrict__ bias, u16* __restrict__ C,
    int M, int N, int K, int ldb, int ldc)
{
    constexpr int BK=32;
    __shared__ u16 As[64][BK+8];
    __shared__ u16 Bs[64][BK+8];
    const int tid = threadIdx.x;
    const int bm = blockIdx.x*64, bn = blockIdx.y*64;
    const int wave = tid>>6, lane = tid&63, lm = lane&15, lg = lane>>4;
    const int wm = (wave>>1)*32, wn = (wave&1)*32;
    f32x4 acc[2][2];
    #pragma unroll
    for(int i=0;i<2;i++){ acc[i][0]=(f32x4){0.f,0.f,0.f,0.f}; acc[i][1]=(f32x4){0.f,0.f,0.f,0.f}; }

    const int arow = tid>>2, akc = (tid&3)*8;
    for(int k0=0;k0<K;k0+=BK){
        *(short8*)&As[arow][akc] = AF32 ? ld8f((const float*)A + (size_t)(bm+arow)*K + k0+akc)
                                        : ld8b((const u16*)A + (size_t)(bm+arow)*K + k0+akc);
        *(short8*)&Bs[arow][akc] = BF32 ? ld8f((const float*)B + (size_t)(bn+arow)*ldb + k0+akc)
                                        : ld8b((const u16*)B + (size_t)(bn+arow)*ldb + k0+akc);
        __syncthreads();
        short8 af[2], bfg[2];
        #pragma unroll
        for(int mt=0;mt<2;mt++) af[mt]  = *(const short8*)&As[wm+mt*16+lm][lg*8];
        #pragma unroll
        for(int nt=0;nt<2;nt++) bfg[nt] = *(const short8*)&Bs[wn+nt*16+lm][lg*8];
        #pragma unroll
        for(int nt=0;nt<2;nt++)
            #pragma unroll
            for(int mt=0;mt<2;mt++)
                acc[mt][nt] = __builtin_amdgcn_mfma_f32_16x16x32_bf16(af[mt], bfg[nt], acc[mt][nt], 0,0,0);
        __syncthreads();
    }
    #pragma unroll
    for(int nt=0;nt<2;nt++){
        const int col = bn+wn+nt*16+lm;
        const float bv = bias ? bias[col] : 0.f;
        #pragma unroll
        for(int mt=0;mt<2;mt++){
            const int row0 = bm+wm+mt*16+lg*4;
            #pragma unroll
            for(int r=0;r<4;r++){
                const int row = row0+r;
                float v = acc[mt][nt][r] + bv;
                if(RELU) v = fmaxf(v, 0.f);
                const size_t idx = TRANSOUT ? ((size_t)col*ldc + row) : ((size_t)row*ldc + col);
                C[idx] = f2b(v);
            }
        }
    }
}

// =============== h1_pre = skill_emb @ gcn_w1^T   (101x8, f32 in/out), 8 blocks ========
__global__ __launch_bounds__(256) void k_h1pre(const float* __restrict__ skill_emb,
                                               const float* __restrict__ gcn_w1,
                                               float* __restrict__ h1pre)
{
    if(threadIdx.x >= 101) return;
    const int idx = blockIdx.x*101 + threadIdx.x;
    if(idx>=808) return;
    const int n=idx>>3, j=idx&7;
    const float* x = skill_emb + n*256;
    const float* w = gcn_w1 + j*256;
    float acc=0.f;
    for(int k=0;k<256;k+=4){
        f32x4 a = *(const f32x4*)&x[k];
        f32x4 b = *(const f32x4*)&w[k];
        acc += a.x*b.x + a.y*b.y + a.z*b.z + a.w*b.w;
    }
    h1pre[idx]=acc;
}

// =============== per-batch skill GCN, softmax pooling -> pooled (64x256 f32) ===============
__global__ __launch_bounds__(256) void k_gcn(
    const int* __restrict__ skill, const int* __restrict__ answer,
    const float* __restrict__ pos, const float* __restrict__ h1pre,
    const float* __restrict__ gcn_b1, const float* __restrict__ gcn_w2, const float* __restrict__ gcn_b2,
    float* __restrict__ pooled)
{
    const int b = blockIdx.x, tid = threadIdx.x;
    __shared__ int   sk[500];
    __shared__ float msk[500];
    __shared__ float coef[500];
    __shared__ float deg[101];
    __shared__ float agg1[101*8];
    __shared__ float agg2[101*8];
    __shared__ float red[256];
    __shared__ float vec8[8];
    __shared__ float sS[1];

    for(int i=tid;i<500;i+=256){
        sk[i]=iclamp(skill[b*500+i],0,100);
        msk[i] = (answer[b*500+i]!=2)?1.f:0.f;
    }
    for(int i=tid;i<101;i+=256) deg[i]=1.f;           // self loop
    if(tid<8)  vec8[tid]=0.f;
    if(tid==8) sS[0]=0.f;
    __syncthreads();
    for(int e=tid;e<499;e+=256) atomicAdd(&deg[sk[e+1]], 1.f);
    __syncthreads();
    for(int i=tid;i<101;i+=256) deg[i] = rsqrtf(deg[i]);   // deg -> dinv
    float cnt=0.f; for(int i=tid;i<500;i+=256) cnt += msk[i];
    __syncthreads();
    red[tid]=cnt; __syncthreads();
    for(int s=128;s>0;s>>=1){ if(tid<s) red[tid]+=red[tid+s]; __syncthreads(); }
    const int len = iclamp((int)(red[0]+0.5f), 1, 500);
    __syncthreads();
    for(int i=tid;i<808;i+=256){ const int n=i>>3; agg1[i] = deg[n]*deg[n]*h1pre[i]; }
    __syncthreads();
    for(int i=tid;i<499*8;i+=256){
        const int e=i>>3, j=i&7, s=sk[e], d=sk[e+1];
        atomicAdd(&agg1[d*8+j], deg[s]*deg[d]*h1pre[s*8+j]);
    }
    __syncthreads();
    for(int i=tid;i<808;i+=256){ const int j=i&7; agg1[i] = fmaxf(agg1[i]+gcn_b1[j], 0.f); }
    __syncthreads();
    for(int i=tid;i<808;i+=256){ const int n=i>>3; agg2[i] = deg[n]*deg[n]*agg1[i]; }
    __syncthreads();
    for(int i=tid;i<499*8;i+=256){
        const int e=i>>3, j=i&7, s=sk[e], d=sk[e+1];
        atomicAdd(&agg2[d*8+j], deg[s]*deg[d]*agg1[s*8+j]);
    }
    const size_t prow = (size_t)(len-1)*500;
    float vmax = -1e30f;
    for(int i=tid;i<500;i+=256){ const float v = pos[prow+i]*msk[i]; coef[i]=v; vmax=fmaxf(vmax,v); }
    red[tid]=vmax; __syncthreads();           // also orders agg2 atomics
    for(int s=128;s>0;s>>=1){ if(tid<s) red[tid]=fmaxf(red[tid],red[tid+s]); __syncthreads(); }
    const float m = red[0]; __syncthreads();
    float lsum=0.f;
    for(int i=tid;i<500;i+=256){ const float e=__expf(coef[i]-m); coef[i]=e; lsum+=e; }
    red[tid]=lsum; __syncthreads();
    for(int s=128;s>0;s>>=1){ if(tid<s) red[tid]+=red[tid+s]; __syncthreads(); }
    const float inv = 1.f/red[0];
    __syncthreads();
    float v8[8]={0,0,0,0,0,0,0,0}; float ls=0.f;
    for(int i=tid;i<500;i+=256){
        const float ci = coef[i]*inv*msk[i];
        if(ci!=0.f){
            const int n=sk[i]; ls+=ci;
            #pragma unroll
            for(int j=0;j<8;j++) v8[j] += ci*agg2[n*8+j];
        }
    }
    #pragma unroll
    for(int j=0;j<8;j++) atomicAdd(&vec8[j], v8[j]);
    atomicAdd(&sS[0], ls);
    __syncthreads();
    {
        const int o = tid;
        float acc = gcn_b2[o]*sS[0];
        #pragma unroll
        for(int j=0;j<8;j++) acc += vec8[j]*gcn_w2[o*8+j];
        pooled[b*256+o] = acc;
    }
}

// ====== x-part tables: table[combo] = x(skill,answer) @ Wih[:,256:768]^T + bih + bhh ======
__global__ __launch_bounds__(256) void k_table(
    const float* __restrict__ skill_emb, const float* __restrict__ answer_emb,
    const float* __restrict__ wih, const float* __restrict__ bih, const float* __restrict__ bhh,
    float* __restrict__ table)
{
    const int combo = blockIdx.x, tid = threadIdx.x;
    const int sid = combo/3, ans = combo - sid*3;
    __shared__ float sf[256], sg[256];
    sf[tid] = (ans==1) ? skill_emb[(size_t)sid*256+tid] : answer_emb[(size_t)ans*256+tid];
    sg[tid] = (ans==1) ? answer_emb[(size_t)ans*256+tid] : skill_emb[(size_t)sid*256+tid];
    __syncthreads();
    const int o = tid;
    float acc = bih[o] + bhh[o];
    const float* w = wih + (size_t)o*768;
    for(int k=0;k<256;k+=4){
        f32x4 w1v = *(const f32x4*)&w[256+k];
        f32x4 w2v = *(const f32x4*)&w[512+k];
        acc += sf[k]*w1v.x + sf[k+1]*w1v.y + sf[k+2]*w1v.z + sf[k+3]*w1v.w;
        acc += sg[k]*w2v.x + sg[k+1]*w2v.y + sg[k+2]*w2v.z + sg[k+3]*w2v.w;
    }
    table[(size_t)combo*256 + o] = acc;
}

// =============== pooled_proj[b] = pooled[b] @ dg_wih[:, :256]^T  (bf16 64x256) ===============
__global__ __launch_bounds__(256) void k_pooledproj(const float* __restrict__ pooled,
                                                    const float* __restrict__ wih,
                                                    u16* __restrict__ outp)
{
    const int b=blockIdx.x, tid=threadIdx.x;
    __shared__ float p[256];
    p[tid] = pooled[b*256+tid];
    __syncthreads();
    const float* w = wih + (size_t)tid*768;
    float acc=0.f;
    for(int k=0;k<256;k+=4){
        f32x4 wv = *(const f32x4*)&w[k];
        acc += p[k]*wv.x + p[k+1]*wv.y + p[k+2]*wv.z + p[k+3]*wv.w;
    }
    outp[b*256+tid]=f2b(acc);
}

// ====== k_pre: pre[rnn][t][b][c] = table[combo(t,b)] + proj  (bf16, t-major) ======
// grid (500, 2, 4), block 256.
__global__ __launch_bounds__(256) void k_pre(
    const int* __restrict__ skill, const int* __restrict__ answer, const int* __restrict__ student,
    const float* __restrict__ table_dg, const float* __restrict__ table_hg,
    const u16* __restrict__ pooled_proj, const u16* __restrict__ stu_proj,
    u16* __restrict__ pre_dg, u16* __restrict__ pre_hg)
{
    const int t = blockIdx.x, rnn = blockIdx.y, c = threadIdx.x;
    const int b0 = blockIdx.z*16;
    const float* tab = rnn ? table_hg : table_dg;
    u16* outp = rnn ? pre_hg : pre_dg;
    for(int b=b0;b<b0+16;b++){
        const int sk = iclamp(skill[b*500+t], 0, 100);
        const int an = iclamp(answer[b*500+t], 0, 2);
        const int cmb = sk*3+an;
        const u16* prow = rnn ? (stu_proj + (size_t)iclamp(student[b*500+t]-1,0,4095)*256)
                              : (pooled_proj + (size_t)b*256);
        const float v = tab[(size_t)cmb*256 + c] + b2f(prow[c]);
        outp[((size_t)t*64+b)*256 + c] = f2b(v);
    }
}

// =============== RNN v6: 4 waves x 4 col-tiles, W register-resident (128 VGPR), no spill ==
// 8 blocks = (rnn, 16-row group); wave owns output cols [wave*64, +64) = 4 col-tiles.
// Per CU-step LDS reads: 4 waves x 8 ds_read_b128 = 32; each read feeds 4 MFMAs.
// All 4 SIMDs issue MFMA (620cy floor) and split the epilogue VALU.
__global__ __launch_bounds__(256,1) void k_rnn(
    const u16* __restrict__ pre_dg, const u16* __restrict__ pre_hg,
    const float* __restrict__ whh_dg, const float* __restrict__ whh_hg,
    u16* __restrict__ hall_dg, u16* __restrict__ hall_hg)
{
    __shared__ u16 hc[2][8][4][16][8];    // 2 x 8KB, fragment chunk layout
    const int bid = blockIdx.x;
    const int rnn = bid>>2, grp = bid&3, rb = grp*16;
    const float* W   = rnn ? whh_hg : whh_dg;
    const u16*  pre  = rnn ? pre_hg : pre_dg;
    u16*        out  = rnn ? hall_hg : hall_dg;
    const int tid = threadIdx.x, wave = tid>>6, lane = tid&63;
    const int lm = lane&15, lg = lane>>4;
    const int cb = wave*64;

    // W fragments as A-operand (row = output col): 4 tiles x 8 kk = 128 VGPRs
    short8 wf[4][8];
    #pragma unroll
    for(int t4=0;t4<4;t4++)
        #pragma unroll
        for(int kk=0;kk<8;kk++)
            wf[t4][kk] = ld8f(W + (size_t)(cb+t4*16+lm)*256 + kk*32 + lg*8);

    for(int i=tid;i<2*8*4*16*8;i+=256) ((u16*)hc)[i]=0;

    const size_t rowoff = (size_t)(rb+lm)*256;
    uint2 pv[4];
    #pragma unroll
    for(int t4=0;t4<4;t4++)
        pv[t4] = *(const uint2*)&pre[rowoff + cb + t4*16 + lg*4];
    __syncthreads();

    int cur = 0;
    for(int t=0;t<500;t++){
        f32x4 acc[4];
        #pragma unroll
        for(int t4=0;t4<4;t4++) acc[t4]=(f32x4){0.f,0.f,0.f,0.f};
        // 8 reads, each feeding 4 MFMAs (4 independent accumulator chains)
        #pragma unroll
        for(int kk=0;kk<8;kk++){
            short8 hb = *(const short8*)&hc[cur][kk][lg][lm][0];
            #pragma unroll
            for(int t4=0;t4<4;t4++)
                acc[t4] = __builtin_amdgcn_mfma_f32_16x16x32_bf16(wf[t4][kk], hb, acc[t4], 0,0,0);
        }
        // prefetch next step's pre
        uint2 pvn[4];
        {
            const int tn = (t<499)? t+1 : 499;
            const size_t base = (size_t)tn*64*256 + rowoff;
            #pragma unroll
            for(int t4=0;t4<4;t4++)
                pvn[t4] = *(const uint2*)&pre[base + cb + t4*16 + lg*4];
        }
        // epilogue: lane holds batch row lm, cols cb+t4*16+lg*4..+3
        #pragma unroll
        for(int t4=0;t4<4;t4++){
            const unsigned plo = pv[t4].x, phi = pv[t4].y;
            u16 hv[4];
            #pragma unroll
            for(int r=0;r<4;r++){
                const u16 pb = (u16)(((r<2)? plo : phi) >> ((r&1)*16));
                const float v = acc[t4][r] + b2f(pb);
                const float e = __expf(2.f*v);
                const float th = 1.f - 2.f*__builtin_amdgcn_rcpf(e+1.f);  // tanh
                hv[r] = f2b_fast(th);
            }
            uint2 pk;
            pk.x = (unsigned)hv[0] | ((unsigned)hv[1]<<16);
            pk.y = (unsigned)hv[2] | ((unsigned)hv[3]<<16);
            // chunk dest for col c = cb+t4*16+lg*4: kk'=wave*2+(t4>>1), lg'=(t4&1)*2+(lg>>1)
            *(uint2*)&hc[cur^1][wave*2+(t4>>1)][(t4&1)*2+(lg>>1)][lm][(lg&1)*4] = pk;
            *(uint2*)&out[(size_t)t*64*256 + rowoff + cb + t4*16 + lg*4] = pk;
        }
        barrier_lds();      // LDS-visibility only: global loads/stores stay in flight
        #pragma unroll
        for(int t4=0;t4<4;t4++) pv[t4]=pvn[t4];
        cur ^= 1;
    }
}

// ====== theta = sigmoid(h_hg@w1^T + h_dg@w2^T + b1 + b2), dual-GEMM fused, bf16 out ======
// grid (250, 4), block 256.  M=32000, N=256, K=256.
__global__ __launch_bounds__(256) void k_theta(
    const u16* __restrict__ Ah, const u16* __restrict__ Ad,
    const float* __restrict__ w1, const float* __restrict__ w2,
    const float* __restrict__ b1, const float* __restrict__ b2,
    u16* __restrict__ theta)
{
    constexpr int BK=32;
    __shared__ u16 AsH[128][BK+8];
    __shared__ u16 AsD[128][BK+8];
    __shared__ u16 BsH[64][BK+8];
    __shared__ u16 BsD[64][BK+8];
    const int tid = threadIdx.x;
    const int bm = blockIdx.x*128, bn = blockIdx.y*64;
    const int wave = tid>>6, lane = tid&63, lm = lane&15, lg = lane>>4;
    const int wm = (wave>>1)*64, wn = (wave&1)*32;
    f32x4 acc[4][2];
    #pragma unroll
    for(int i=0;i<4;i++){ acc[i][0]=(f32x4){0.f,0.f,0.f,0.f}; acc[i][1]=(f32x4){0.f,0.f,0.f,0.f}; }

    const int arow0 = tid>>2, akc0 = (tid&3)*8;
    const int arow1 = arow0 + 64;
    for(int k0=0;k0<256;k0+=BK){
        *(short8*)&AsH[arow0][akc0] = ld8b(Ah + (size_t)(bm+arow0)*256 + k0+akc0);
        *(short8*)&AsH[arow1][akc0] = ld8b(Ah + (size_t)(bm+arow1)*256 + k0+akc0);
        *(short8*)&AsD[arow0][akc0] = ld8b(Ad + (size_t)(bm+arow0)*256 + k0+akc0);
        *(short8*)&AsD[arow1][akc0] = ld8b(Ad + (size_t)(bm+arow1)*256 + k0+akc0);
        *(short8*)&BsH[arow0][akc0] = ld8f(w1 + (size_t)(bn+arow0)*256 + k0+akc0);
        *(short8*)&BsD[arow0][akc0] = ld8f(w2 + (size_t)(bn+arow0)*256 + k0+akc0);
        __syncthreads();
        short8 afH[4], afD[4], bf1[2], bf2[2];
        #pragma unroll
        for(int mt=0;mt<4;mt++){
            afH[mt] = *(const short8*)&AsH[wm+mt*16+lm][lg*8];
            afD[mt] = *(const short8*)&AsD[wm+mt*16+lm][lg*8];
        }
        #pragma unroll
        for(int nt=0;nt<2;nt++){
            bf1[nt] = *(const short8*)&BsH[wn+nt*16+lm][lg*8];
            bf2[nt] = *(const short8*)&BsD[wn+nt*16+lm][lg*8];
        }
        #pragma unroll
        for(int nt=0;nt<2;nt++)
            #pragma unroll
            for(int mt=0;mt<4;mt++){
                acc[mt][nt] = __builtin_amdgcn_mfma_f32_16x16x32_bf16(afH[mt], bf1[nt], acc[mt][nt], 0,0,0);
                acc[mt][nt] = __builtin_amdgcn_mfma_f32_16x16x32_bf16(afD[mt], bf2[nt], acc[mt][nt], 0,0,0);
            }
        __syncthreads();
    }
    #pragma unroll
    for(int nt=0;nt<2;nt++){
        const int col = bn+wn+nt*16+lm;
        const float bb = b1[col]+b2[col];
        #pragma unroll
        for(int mt=0;mt<4;mt++){
            const int row0 = bm+wm+mt*16+lg*4;
            #pragma unroll
            for(int r=0;r<4;r++){
                const float x = acc[mt][nt][r] + bb;
                theta[(size_t)(row0+r)*256 + col] = f2b(1.f/(1.f+__expf(-x)));
            }
        }
    }
}

// =============== final gather: one wave per (b,t), three outputs ===============
__global__ __launch_bounds__(256) void k_out(
    const int* __restrict__ skill,
    const u16* __restrict__ hall_hg, const u16* __restrict__ hall_dg,
    const u16* __restrict__ theta,
    const float* __restrict__ fc_h_w, const float* __restrict__ fc_h_b,
    const float* __restrict__ fc_d_w, const float* __restrict__ fc_d_b,
    const float* __restrict__ fc_e_w, const float* __restrict__ fc_e_b,
    float* __restrict__ outp)
{
    const int tid=threadIdx.x, lane=tid&63;
    const int wid = blockIdx.x*4 + (tid>>6);        // 0..31935
    const int b = wid/499, t = wid - b*499;
    const int ns = skill[b*500 + t + 1];
    float o0=0.f,o1=0.f,o2=0.f,bh=0.f,bd=0.f,be=0.f;
    if(ns != 100){
        const int c = iclamp(ns, 0, 99);
        const size_t r = (size_t)t*64 + b;
        const int k = lane*4;
        short4v hh  = *(const short4v*)&hall_hg[r*256+k];
        short4v hd  = *(const short4v*)&hall_dg[r*256+k];
        short4v th  = *(const short4v*)&theta[r*256+k];
        f32x4 fh  = *(const f32x4*)&fc_h_w[(size_t)c*256+k];
        f32x4 fd  = *(const f32x4*)&fc_d_w[(size_t)c*256+k];
        f32x4 fe1 = *(const f32x4*)&fc_e_w[(size_t)c*512+k];
        f32x4 fe2 = *(const f32x4*)&fc_e_w[(size_t)c*512+256+k];
        #pragma unroll
        for(int j=0;j<4;j++){
            const float hhj=b2f((u16)hh[j]), hdj=b2f((u16)hd[j]), tj=b2f((u16)th[j]);
            o0 += hhj*fh[j];
            o1 += hdj*fd[j];
            o2 += tj*hhj*fe1[j] + (1.f-tj)*hdj*fe2[j];
        }
        #pragma unroll
        for(int off=32;off>0;off>>=1){
            o0 += __shfl_down(o0,off);
            o1 += __shfl_down(o1,off);
            o2 += __shfl_down(o2,off);
        }
        bh=fc_h_b[c]; bd=fc_d_b[c]; be=fc_e_b[c];
    }
    if(lane==0){
        outp[            b*499+t] = (ns==100)?0.f:(o0+bh);
        outp[31936     + b*499+t] = (ns==100)?0.f:(o1+bd);
        outp[2*31936   + b*499+t] = (ns==100)?0.f:(o2+be);
    }
}

// ================================= launch =================================
extern "C" void kernel_launch(void* const* d_in, const int* in_sizes, int n_in,
                              void* d_out, int out_size, void* d_ws, size_t ws_size,
                              hipStream_t stream)
{
    const int* student = (const int*)d_in[0];
    const int* skill   = (const int*)d_in[1];
    const int* answer  = (const int*)d_in[2];
    const float* G        = (const float*)d_in[3];
    const float* skill_emb= (const float*)d_in[4];
    const float* answer_emb=(const float*)d_in[5];
    const float* stu      = (const float*)d_in[6];
    const float* hg_w1    = (const float*)d_in[7];
    const float* hg_b1    = (const float*)d_in[8];
    const float* hg_w2    = (const float*)d_in[9];
    const float* hg_b2    = (const float*)d_in[10];
    const float* gcn_w1   = (const float*)d_in[11];
    const float* gcn_b1   = (const float*)d_in[12];
    const float* gcn_w2   = (const float*)d_in[13];
    const float* gcn_b2   = (const float*)d_in[14];
    const float* w1_w     = (const float*)d_in[15];
    const float* w1_b     = (const float*)d_in[16];
    const float* w2_w     = (const float*)d_in[17];
    const float* w2_b     = (const float*)d_in[18];
    const float* fc_d_w   = (const float*)d_in[19];
    const float* fc_d_b   = (const float*)d_in[20];
    const float* fc_h_w   = (const float*)d_in[21];
    const float* fc_h_b   = (const float*)d_in[22];
    const float* fc_e_w   = (const float*)d_in[23];
    const float* fc_e_b   = (const float*)d_in[24];
    const float* pos      = (const float*)d_in[25];
    const float* dg_wih   = (const float*)d_in[26];
    const float* dg_whh   = (const float*)d_in[27];
    const float* dg_bih   = (const float*)d_in[28];
    const float* dg_bhh   = (const float*)d_in[29];
    const float* hgr_wih  = (const float*)d_in[30];
    const float* hgr_whh  = (const float*)d_in[31];
    const float* hgr_bih  = (const float*)d_in[32];
    const float* hgr_bhh  = (const float*)d_in[33];

    char* ws = (char*)d_ws;
    size_t off = 0;
    auto nxt = [&](size_t bytes)->char*{
        char* r = ws + off;
        off += (bytes + 255) & ~(size_t)255;
        return r;
    };
    float* h1pre      = (float*)nxt(808*4);
    float* pooled     = (float*)nxt(64*256*4);
    float* table_dg   = (float*)nxt(303*256*4);
    float* table_hg   = (float*)nxt(303*256*4);
    u16*   tmpT       = (u16*)  nxt((size_t)256*4096*2);
    u16*   hbuf       = (u16*)  nxt((size_t)4096*256*2);
    u16*   stu_proj   = (u16*)  nxt((size_t)4096*256*2);
    u16*   pooled_proj= (u16*)  nxt(64*256*2);
    u16*   hall_dg    = (u16*)  nxt((size_t)32000*256*2);   // 16.4 MB
    u16*   hall_hg    = (u16*)  nxt((size_t)32000*256*2);   // 16.4 MB
    u16*   pre_dg     = (u16*)  nxt((size_t)32000*256*2);   // 16.4 MB (reused as theta)
    u16*   pre_hg     = (u16*)  nxt((size_t)32000*256*2);   // 16.4 MB
    u16*   theta      = pre_dg;                              // pre_dg dead after k_rnn

    // small prep
    k_h1pre<<<8,256,0,stream>>>(skill_emb, gcn_w1, h1pre);
    k_gcn<<<64,256,0,stream>>>(skill, answer, pos, h1pre, gcn_b1, gcn_w2, gcn_b2, pooled);
    k_table<<<303,256,0,stream>>>(skill_emb, answer_emb, dg_wih,  dg_bih,  dg_bhh,  table_dg);
    k_table<<<303,256,0,stream>>>(skill_emb, answer_emb, hgr_wih, hgr_bih, hgr_bhh, table_hg);

    // student GCN chain (G read as f32 directly; staging converts)
    gemm64<true ,false,true ,true ><<<dim3(64,4),256,0,stream>>>(stu,  hg_w1, hg_b1, tmpT, 4096,256,256,  256, 4096);
    gemm64<false,true ,true ,false><<<dim3(64,4),256,0,stream>>>(G,    tmpT,  nullptr, hbuf, 4096,256,4096, 4096, 256);
    gemm64<true ,false,false,true ><<<dim3(64,4),256,0,stream>>>(hbuf, hg_w2, hg_b2, tmpT, 4096,256,256,  256, 4096);
    gemm64<false,false,true ,false><<<dim3(64,4),256,0,stream>>>(G,    tmpT,  nullptr, hbuf, 4096,256,4096, 4096, 256);
    gemm64<false,false,false,true ><<<dim3(64,4),256,0,stream>>>(hbuf, hgr_wih, nullptr, stu_proj, 4096,256,256, 768, 256);

    k_pooledproj<<<64,256,0,stream>>>(pooled, dg_wih, pooled_proj);

    // fused pre-activation array (t-major bf16), indices inline
    k_pre<<<dim3(500,2,4),256,0,stream>>>(skill, answer, student, table_dg, table_hg,
                                          pooled_proj, stu_proj, pre_dg, pre_hg);

    // recurrences: 4 waves per block, W register-resident, no spill
    k_rnn<<<8,256,0,stream>>>(pre_dg, pre_hg, dg_whh, hgr_whh, hall_dg, hall_hg);

    // theta + outputs
    k_theta<<<dim3(250,4),256,0,stream>>>(hall_hg, hall_dg, w1_w, w2_w, w1_b, w2_b, theta);
    k_out<<<7984,256,0,stream>>>(skill, hall_hg, hall_dg, theta,
                                 fc_h_w, fc_h_b, fc_d_w, fc_d_b, fc_e_w, fc_e_b,
                                 (float*)d_out);
}